// Round 8
// baseline (103.031 us; speedup 1.0000x reference)
//
#include <hip/hip_runtime.h>
#include <hip/hip_bf16.h>

typedef __bf16 bf16x8 __attribute__((ext_vector_type(8)));
typedef float  f32x4  __attribute__((ext_vector_type(4)));

#define HW       3136
#define IMG_W    56
#define IMG_H    56
#define XT_ROW_B 16384                     // 64 cols * 128ch * 2B
#define XT_IMG_B (58*XT_ROW_B)             // 950272
#define XT_BYTES ((size_t)32*XT_IMG_B)     // ~30.4 MB
#define WGRAN    (9*128*16)                // 16B granules in W
#define WB_BYTES ((size_t)WGRAN*16)        // 294912
#define PBLK     (32*58)                   // prepass blocks
#define NTILES   896                       // 32 img * 28 row-pairs
#define CBLK     256                       // persistent conv blocks (1/CU)

// ---- weight fp32 -> bf16, fragment-major layout:
//      [tap][q32][c][f][lq][l15] granules of 16B, so a wave's 8 A-frags for
//      one tap are 8 contiguous-1KB wave-loads at lane*16 + (c*2+f)*1024 ----
__global__ __launch_bounds__(256) void wcvt_kernel(const float* __restrict__ w,
                                                   unsigned char* __restrict__ wb) {
    int i = blockIdx.x * 256 + threadIdx.x;          // one 16B granule each
    if (i >= WGRAN) return;
    const int l15 = i & 15, lq = (i >> 4) & 3, f = (i >> 6) & 1;
    const int c   = (i >> 7) & 3, q32 = (i >> 9) & 3, tap = i >> 11;
    const int oc = q32 * 32 + f * 16 + l15;
    const int ch = c * 32 + lq * 8;
    const float* src = w + (size_t)(tap * 128 + oc) * 128 + ch;
    bf16x8 v;
    #pragma unroll
    for (int j = 0; j < 8; ++j) v[j] = (__bf16)src[j];
    *(bf16x8*)(wb + (size_t)i * 16) = v;
}

// ---- prepass: x [n][c][h][w] fp32 -> xt [n][58][64][128] bf16,
//      zero borders, XOR swizzle ((col&7) granules) baked into layout ----
__global__ __launch_bounds__(256) void xprep_kernel(const float* __restrict__ x,
                                                    unsigned char* __restrict__ xt) {
    __shared__ float ldsF[128 * 65];
    const int bid = blockIdx.x;
    const int swz = (bid & 7) * (PBLK / 8) + (bid >> 3);
    const int n = swz / 58, rt = swz - n * 58;
    unsigned char* row = xt + (size_t)n * XT_IMG_B + (size_t)rt * XT_ROW_B;
    const int t = threadIdx.x;

    if (rt == 0 || rt == 57) {            // zero border rows
        f32x4 z = {0.f, 0.f, 0.f, 0.f};
        #pragma unroll
        for (int i = 0; i < 4; ++i) *(f32x4*)(row + t * 64 + i * 16) = z;
        return;
    }
    const int r = rt - 1;
    const float* xr = x + (size_t)n * 128 * HW + (size_t)r * IMG_W;
    const int wv = t >> 6, lane = t & 63;
    const int wi = min(lane, IMG_W - 1);
    #pragma unroll
    for (int cc = 0; cc < 32; ++cc) {
        int c = cc * 4 + wv;
        float v = xr[(size_t)c * HW + wi];
        ldsF[c * 65 + lane] = (lane < IMG_W) ? v : 0.f;
    }
    __syncthreads();

    const int cl = t >> 2, q = t & 3;     // col 0..63, channel quarter
    const bool inb = (cl >= 1) && (cl <= 56);
    #pragma unroll
    for (int g4 = 0; g4 < 4; ++g4) {
        int gi = q * 4 + g4;              // granule = channels gi*8..gi*8+7
        bf16x8 pk;
        #pragma unroll
        for (int j = 0; j < 8; ++j)
            pk[j] = inb ? (__bf16)ldsF[(gi * 8 + j) * 65 + (cl - 1)] : (__bf16)0.0f;
        *(bf16x8*)(row + cl * 256 + ((gi ^ (cl & 7)) * 16)) = pk;
    }
}

// ---- per-tile x stage: 64KB linear global_load_lds (16B/lane) ----
__device__ __forceinline__ void stage_tile(const unsigned char* __restrict__ xt,
                                           unsigned char* dst, int tile, int t, int wv) {
    const int n = tile / 28, rp = tile - n * 28;
    const unsigned char* src = xt + (size_t)n * XT_IMG_B + (size_t)(rp * 2) * XT_ROW_B;
    #pragma unroll
    for (int i = 0; i < 8; ++i) {
        __builtin_amdgcn_global_load_lds(
            (const __attribute__((address_space(1))) unsigned int*)(src + i * 8192 + t * 16),
            (__attribute__((address_space(3))) unsigned int*)(dst + i * 8192 + wv * 1024),
            16, 0, 0);
    }
}

// ---- compute one 2-row tile: wave = 32 oc x NPF*16 pos, A reg-dbuf (r7 body) ----
template<int NPF>
__device__ __forceinline__ void compute_store(const unsigned char* xs, const __bf16* wt,
                                              float* on, int oc0, int pf0, int r0, int lane) {
    const int l15 = lane & 15, lq = lane >> 4;
    int vb[NPF], scol[NPF];
    #pragma unroll
    for (int k = 0; k < NPF; ++k) {
        int p = (pf0 + k) * 16 + l15;     // 0..111 block-local pos
        int pr = p / 56, pc = p - pr * 56;
        vb[k]   = ((pr + 1) * 64 + (pc + 1)) * 256;
        scol[k] = pc + 1;
    }
    f32x4 acc[2][NPF];
    #pragma unroll
    for (int f = 0; f < 2; ++f)
        #pragma unroll
        for (int k = 0; k < NPF; ++k) acc[f][k] = (f32x4){0.f, 0.f, 0.f, 0.f};

    // A register double-buffer: aB[buf][f*4+c], buf/tap indices static after unroll
    bf16x8 aB[2][8];
    #pragma unroll
    for (int i = 0; i < 8; ++i)
        aB[0][i] = *(const bf16x8*)(wt + ((i & 3) * 2 + (i >> 2)) * 512);

    #pragma unroll
    for (int tap = 0; tap < 9; ++tap) {
        if (tap < 8) {                    // issue next tap's 8 frag loads (1KB coalesced each)
            const __bf16* wn = wt + (tap + 1) * 16384;
            #pragma unroll
            for (int i = 0; i < 8; ++i)
                aB[(tap + 1) & 1][i] = *(const bf16x8*)(wn + ((i & 3) * 2 + (i >> 2)) * 512);
        }
        __builtin_amdgcn_sched_barrier(0);   // pin load-issue before the MFMA cluster

        const int dh = tap / 3 - 1, dw = tap - (tap / 3) * 3 - 1;
        int base[NPF], sw[NPF];
        #pragma unroll
        for (int k = 0; k < NPF; ++k) {
            base[k] = vb[k] + (dh * 64 + dw) * 256;
            sw[k]   = (scol[k] + dw) & 7;
        }
        __builtin_amdgcn_s_setprio(1);
        #pragma unroll
        for (int c = 0; c < 4; ++c) {
            #pragma unroll
            for (int k = 0; k < NPF; ++k) {
                int gi = ((c * 4 + lq) ^ sw[k]) * 16;
                bf16x8 b = *(const bf16x8*)(xs + base[k] + gi);
                acc[0][k] = __builtin_amdgcn_mfma_f32_16x16x32_bf16(aB[tap & 1][c],     b, acc[0][k], 0, 0, 0);
                acc[1][k] = __builtin_amdgcn_mfma_f32_16x16x32_bf16(aB[tap & 1][4 + c], b, acc[1][k], 0, 0, 0);
            }
        }
        __builtin_amdgcn_s_setprio(0);
        __builtin_amdgcn_sched_barrier(0);   // keep next iteration's loads out of this cluster
    }

    #pragma unroll
    for (int f = 0; f < 2; ++f)
        #pragma unroll
        for (int k = 0; k < NPF; ++k) {
            int pos = r0 * 56 + (pf0 + k) * 16 + l15;
            int oc  = oc0 + f * 16 + lq * 4;
            #pragma unroll
            for (int rr = 0; rr < 4; ++rr)
                on[(size_t)(oc + rr) * HW + pos] = acc[f][k][rr];
        }
}

// ---- persistent conv: 256 blocks, 3-4 tiles each, x double-buffered in LDS ----
__global__ __launch_bounds__(512, 2) void conv_kernel(const unsigned char* __restrict__ xt,
                                                      const unsigned char* __restrict__ wb,
                                                      float* __restrict__ out) {
    __shared__ __align__(16) unsigned char smem[131072];   // 2 x 64KB x-tile buffers
    const int t = threadIdx.x, lane = t & 63, wv = t >> 6;  // 8 waves
    const int b = blockIdx.x;
    const int swz = (b & 7) * 32 + (b >> 3);                // XCD-contiguous tile runs
    const int t0 = (swz * 7) >> 1;
    const int t1 = ((swz + 1) * 7) >> 1;                    // 3 or 4 tiles

    const int oc0 = (wv & 3) * 32;
    const __bf16* wt = (const __bf16*)(wb + (size_t)(wv & 3) * 8192 + lane * 16);

    // prologue: stage first two tiles, wait only for the first
    stage_tile(xt, smem, t0, t, wv);
    stage_tile(xt, smem + 65536, t0 + 1, t, wv);
    asm volatile("s_waitcnt vmcnt(8)" ::: "memory");        // own tile-0 stage done
    __builtin_amdgcn_sched_barrier(0);
    __builtin_amdgcn_s_barrier();                            // all waves' tile-0 done
    __builtin_amdgcn_sched_barrier(0);

    for (int tt = t0; tt < t1; ++tt) {
        unsigned char* cur = smem + (size_t)((tt - t0) & 1) * 65536;
        const int n = tt / 28, r0 = (tt - n * 28) * 2;
        float* on = out + (size_t)n * 128 * HW;

        // compute(t): per-wave counted A-load waits also retire the (older)
        // stage(t+1) ops, so after the barrier below buf[(t+1)&1] is ready.
        if (wv < 4) compute_store<4>(cur, wt, on, oc0, 0, r0, lane);
        else        compute_store<3>(cur, wt, on, oc0, 4, r0, lane);

        __builtin_amdgcn_sched_barrier(0);
        __builtin_amdgcn_s_barrier();        // all waves done reading cur (MFMA operand
        __builtin_amdgcn_sched_barrier(0);   // waits serviced every ds_read pre-barrier)

        if (tt + 2 < t1) stage_tile(xt, cur, tt + 2, t, wv);   // overwrite freed buffer
    }
}

// ================= fallback (ws too small): self-contained, fp32 weights =================
#define PITCH  272
#define LDSB   (4*64*PITCH)
#define NBLK   896

template<int NPF>
__device__ __forceinline__ void fb_compute(const unsigned char* xs, const float* wf,
                                           float* on, int oc0, int pf0, int r0, int lane) {
    const int l15 = lane & 15, lq = lane >> 4;
    int spb[NPF];
    #pragma unroll
    for (int k = 0; k < NPF; ++k) {
        int p = (pf0 + k) * 16 + l15;
        int r = p / 56, w = p - r * 56;
        spb[k] = ((r + 1) * 64 + (w + 1)) * PITCH + lq * 16;
    }
    f32x4 acc[2][NPF];
    #pragma unroll
    for (int f = 0; f < 2; ++f)
        #pragma unroll
        for (int k = 0; k < NPF; ++k) acc[f][k] = (f32x4){0.f, 0.f, 0.f, 0.f};
    #pragma unroll 3
    for (int tap = 0; tap < 9; ++tap) {
        const int offb  = ((tap / 3) * 64 + (tap % 3) - 65) * PITCH;
        const int wbase = tap * 16384 + oc0 * 128 + l15 * 128 + lq * 8;
        #pragma unroll
        for (int c = 0; c < 4; ++c) {
            bf16x8 a[2];
            #pragma unroll
            for (int f = 0; f < 2; ++f) {
                const float* p = wf + wbase + f * 2048 + c * 32;
                #pragma unroll
                for (int j = 0; j < 8; ++j) a[f][j] = (__bf16)p[j];
            }
            #pragma unroll
            for (int k = 0; k < NPF; ++k) {
                bf16x8 b = *(const bf16x8*)(xs + spb[k] + offb + c * 64);
                #pragma unroll
                for (int f = 0; f < 2; ++f)
                    acc[f][k] = __builtin_amdgcn_mfma_f32_16x16x32_bf16(a[f], b, acc[f][k], 0, 0, 0);
            }
        }
    }
    #pragma unroll
    for (int f = 0; f < 2; ++f)
        #pragma unroll
        for (int k = 0; k < NPF; ++k) {
            int pos = r0 * 56 + (pf0 + k) * 16 + l15;
            int oc  = oc0 + f * 16 + lq * 4;
            #pragma unroll
            for (int rr = 0; rr < 4; ++rr)
                on[(size_t)(oc + rr) * HW + pos] = acc[f][k][rr];
        }
}

__global__ __launch_bounds__(512, 4) void fb_conv_kernel(const float* __restrict__ x,
                                                         const float* __restrict__ wf,
                                                         float* __restrict__ out) {
    __shared__ __align__(16) unsigned char xs[LDSB];
    const int tid = threadIdx.x, lane = tid & 63, wv = tid >> 6;
    const int bid = blockIdx.x;
    const int swz = (bid & 7) * (NBLK / 8) + (bid >> 3);
    const int n = swz / 28, rp = swz - n * 28, r0 = rp * 2;
    if (wv < 4) {
        const float* xn = x + (size_t)n * 128 * HW;
        const int ar = r0 - 1 + wv, wi = lane - 1;
        const bool v = (ar >= 0) & (ar < IMG_H) & (wi >= 0) & (wi < IMG_W);
        const int gc = min(max(ar, 0), IMG_H - 1) * IMG_W + min(max(wi, 0), IMG_W - 1);
        unsigned char* dst = xs + (wv * 64 + lane) * PITCH;
        #pragma unroll
        for (int cg = 0; cg < 16; ++cg) {
            bf16x8 pk;
            #pragma unroll
            for (int j = 0; j < 8; ++j) {
                float f = xn[(size_t)(cg * 8 + j) * HW + gc];
                pk[j] = (__bf16)(v ? f : 0.f);
            }
            *(bf16x8*)(dst + cg * 16) = pk;
        }
    }
    __syncthreads();
    const int oc0 = (wv & 3) * 32;
    float* on = out + (size_t)n * 128 * HW;
    if (wv < 4) fb_compute<4>(xs, wf, on, oc0, 0, r0, lane);
    else        fb_compute<3>(xs, wf, on, oc0, 4, r0, lane);
}

extern "C" void kernel_launch(void* const* d_in, const int* in_sizes, int n_in,
                              void* d_out, int out_size, void* d_ws, size_t ws_size,
                              hipStream_t stream) {
    const float* x = (const float*)d_in[0];
    const float* w = (const float*)d_in[1];
    float* out = (float*)d_out;

    if (ws_size >= XT_BYTES + WB_BYTES) {
        unsigned char* xt = (unsigned char*)d_ws;
        unsigned char* wb = xt + XT_BYTES;
        wcvt_kernel<<<(WGRAN + 255) / 256, 256, 0, stream>>>(w, wb);
        xprep_kernel<<<PBLK, 256, 0, stream>>>(x, xt);
        conv_kernel<<<CBLK, 512, 0, stream>>>(xt, wb, out);
    } else {
        fb_conv_kernel<<<NBLK, 512, 0, stream>>>(x, w, out);
    }
}

// Round 9
// 63.417 us; speedup vs baseline: 1.6247x; 1.6247x over previous
//
#include <hip/hip_runtime.h>
#include <hip/hip_bf16.h>

typedef __bf16 bf16x8 __attribute__((ext_vector_type(8)));
typedef float  f32x4  __attribute__((ext_vector_type(4)));

#define HW       3136
#define IMG_W    56
#define IMG_H    56
#define XT_ROW_B 16384                     // 64 cols * 128ch * 2B
#define XT_IMG_B (58*XT_ROW_B)             // 950272
#define XT_BYTES ((size_t)32*XT_IMG_B)     // ~30.4 MB
#define WGRAN    (9*128*16)                // 16B granules in W
#define WB_BYTES ((size_t)WGRAN*16)        // 294912
#define PBLK     (32*58)                   // prepass blocks
#define CBLK     224                       // conv blocks: 7 per image, 4 tiles each

// ---- weight fp32 -> bf16, fragment-major layout:
//      [tap][q32][c][f][lq][l15] granules of 16B ----
__global__ __launch_bounds__(256) void wcvt_kernel(const float* __restrict__ w,
                                                   unsigned char* __restrict__ wb) {
    int i = blockIdx.x * 256 + threadIdx.x;          // one 16B granule each
    if (i >= WGRAN) return;
    const int l15 = i & 15, lq = (i >> 4) & 3, f = (i >> 6) & 1;
    const int c   = (i >> 7) & 3, q32 = (i >> 9) & 3, tap = i >> 11;
    const int oc = q32 * 32 + f * 16 + l15;
    const int ch = c * 32 + lq * 8;
    const float* src = w + (size_t)(tap * 128 + oc) * 128 + ch;
    bf16x8 v;
    #pragma unroll
    for (int j = 0; j < 8; ++j) v[j] = (__bf16)src[j];
    *(bf16x8*)(wb + (size_t)i * 16) = v;
}

// ---- prepass: x [n][c][h][w] fp32 -> xt [n][58][64][128] bf16,
//      zero borders, XOR swizzle ((col&7) granules) baked into layout ----
__global__ __launch_bounds__(256) void xprep_kernel(const float* __restrict__ x,
                                                    unsigned char* __restrict__ xt) {
    __shared__ float ldsF[128 * 65];
    const int bid = blockIdx.x;
    const int swz = (bid & 7) * (PBLK / 8) + (bid >> 3);
    const int n = swz / 58, rt = swz - n * 58;
    unsigned char* row = xt + (size_t)n * XT_IMG_B + (size_t)rt * XT_ROW_B;
    const int t = threadIdx.x;

    if (rt == 0 || rt == 57) {            // zero border rows
        f32x4 z = {0.f, 0.f, 0.f, 0.f};
        #pragma unroll
        for (int i = 0; i < 4; ++i) *(f32x4*)(row + t * 64 + i * 16) = z;
        return;
    }
    const int r = rt - 1;
    const float* xr = x + (size_t)n * 128 * HW + (size_t)r * IMG_W;
    const int wv = t >> 6, lane = t & 63;
    const int wi = min(lane, IMG_W - 1);
    #pragma unroll
    for (int cc = 0; cc < 32; ++cc) {
        int c = cc * 4 + wv;
        float v = xr[(size_t)c * HW + wi];
        ldsF[c * 65 + lane] = (lane < IMG_W) ? v : 0.f;
    }
    __syncthreads();

    const int cl = t >> 2, q = t & 3;     // col 0..63, channel quarter
    const bool inb = (cl >= 1) && (cl <= 56);
    #pragma unroll
    for (int g4 = 0; g4 < 4; ++g4) {
        int gi = q * 4 + g4;              // granule = channels gi*8..gi*8+7
        bf16x8 pk;
        #pragma unroll
        for (int j = 0; j < 8; ++j)
            pk[j] = inb ? (__bf16)ldsF[(gi * 8 + j) * 65 + (cl - 1)] : (__bf16)0.0f;
        *(bf16x8*)(row + cl * 256 + ((gi ^ (cl & 7)) * 16)) = pk;
    }
}

// ---- issue 64KB linear global_load_lds stage (8 x 16B per thread) ----
__device__ __forceinline__ void stage_issue(const unsigned char* src,
                                            unsigned char* dst, int t, int wv) {
    #pragma unroll
    for (int i = 0; i < 8; ++i) {
        __builtin_amdgcn_global_load_lds(
            (const __attribute__((address_space(1))) unsigned int*)(src + i * 8192 + t * 16),
            (__attribute__((address_space(3))) unsigned int*)(dst + i * 8192 + wv * 1024),
            16, 0, 0);
    }
}

// ---- compute one 2-row tile; optionally issue next-next tile's stage at tap 3 ----
template<int NPF, bool STG>
__device__ __forceinline__ void compute_store(const unsigned char* xs, const __bf16* wt,
                                              float* on, int oc0, int pf0, int r0, int lane,
                                              const unsigned char* ssrc, unsigned char* sdst,
                                              int t, int wv) {
    const int l15 = lane & 15, lq = lane >> 4;
    int vb[NPF], scol[NPF];
    #pragma unroll
    for (int k = 0; k < NPF; ++k) {
        int p = (pf0 + k) * 16 + l15;     // 0..111 block-local pos
        int pr = p / 56, pc = p - pr * 56;
        vb[k]   = ((pr + 1) * 64 + (pc + 1)) * 256;
        scol[k] = pc + 1;
    }
    f32x4 acc[2][NPF];
    #pragma unroll
    for (int f = 0; f < 2; ++f)
        #pragma unroll
        for (int k = 0; k < NPF; ++k) acc[f][k] = (f32x4){0.f, 0.f, 0.f, 0.f};

    // A register double-buffer: all indices static after unroll
    bf16x8 aB[2][8];
    #pragma unroll
    for (int i = 0; i < 8; ++i)
        aB[0][i] = *(const bf16x8*)(wt + ((i & 3) * 2 + (i >> 2)) * 512);

    #pragma unroll
    for (int tap = 0; tap < 9; ++tap) {
        if (tap < 8) {                    // issue next tap's 8 frag loads
            const __bf16* wn = wt + (tap + 1) * 16384;
            #pragma unroll
            for (int i = 0; i < 8; ++i)
                aB[(tap + 1) & 1][i] = *(const bf16x8*)(wn + ((i & 3) * 2 + (i >> 2)) * 512);
        }
        if (STG && tap == 3)              // stage next-next tile; drains at tap5's
            stage_issue(ssrc, sdst, t, wv);   // vmcnt(0) with ~2-tap head start
        __builtin_amdgcn_sched_barrier(0);   // pin load-issue before the MFMA cluster

        const int dh = tap / 3 - 1, dw = tap - (tap / 3) * 3 - 1;
        int base[NPF], sw[NPF];
        #pragma unroll
        for (int k = 0; k < NPF; ++k) {
            base[k] = vb[k] + (dh * 64 + dw) * 256;
            sw[k]   = (scol[k] + dw) & 7;
        }
        __builtin_amdgcn_s_setprio(1);
        #pragma unroll
        for (int c = 0; c < 4; ++c) {
            #pragma unroll
            for (int k = 0; k < NPF; ++k) {
                int gi = ((c * 4 + lq) ^ sw[k]) * 16;
                bf16x8 b = *(const bf16x8*)(xs + base[k] + gi);
                acc[0][k] = __builtin_amdgcn_mfma_f32_16x16x32_bf16(aB[tap & 1][c],     b, acc[0][k], 0, 0, 0);
                acc[1][k] = __builtin_amdgcn_mfma_f32_16x16x32_bf16(aB[tap & 1][4 + c], b, acc[1][k], 0, 0, 0);
            }
        }
        __builtin_amdgcn_s_setprio(0);
        __builtin_amdgcn_sched_barrier(0);
    }

    #pragma unroll
    for (int f = 0; f < 2; ++f)
        #pragma unroll
        for (int k = 0; k < NPF; ++k) {
            int pos = r0 * 56 + (pf0 + k) * 16 + l15;
            int oc  = oc0 + f * 16 + lq * 4;
            #pragma unroll
            for (int rr = 0; rr < 4; ++rr)
                on[(size_t)(oc + rr) * HW + pos] = acc[f][k][rr];
        }
}

// ---- conv: 224 blocks x 4 tiles, fully static double-buffered pipeline ----
__global__ __launch_bounds__(512, 2) void conv_kernel(const unsigned char* __restrict__ xt,
                                                      const unsigned char* __restrict__ wb,
                                                      float* __restrict__ out) {
    __shared__ __align__(16) unsigned char smem[131072];   // 2 x 64KB x-tile buffers
    unsigned char* bufA = smem;
    unsigned char* bufB = smem + 65536;

    const int t = threadIdx.x, lane = t & 63, wv = t >> 6;  // 8 waves
    const int b = blockIdx.x;
    const int swz = (b & 7) * 28 + (b >> 3);                // XCD-contiguous: 4 img/XCD
    const int img = swz / 7, loc = swz - img * 7;           // 4 tiles: rp = loc*4..loc*4+3
    const int rp0 = loc * 4;

    const unsigned char* xi = xt + (size_t)img * XT_IMG_B;
    const unsigned char* s0 = xi + (size_t)(rp0 * 2 + 0) * XT_ROW_B;
    const unsigned char* s1 = xi + (size_t)(rp0 * 2 + 2) * XT_ROW_B;
    const unsigned char* s2 = xi + (size_t)(rp0 * 2 + 4) * XT_ROW_B;
    const unsigned char* s3 = xi + (size_t)(rp0 * 2 + 6) * XT_ROW_B;

    const int oc0 = (wv & 3) * 32;
    const __bf16* wt = (const __bf16*)(wb + (size_t)(wv & 3) * 8192 + lane * 16);
    float* on = out + (size_t)img * 128 * HW;

    stage_issue(s0, bufA, t, wv);
    stage_issue(s1, bufB, t, wv);
    asm volatile("s_waitcnt vmcnt(8)" ::: "memory");        // bufA stage done
    __builtin_amdgcn_sched_barrier(0);
    __builtin_amdgcn_s_barrier();
    __builtin_amdgcn_sched_barrier(0);

    // T0 from bufA (bufB stage drains at tap0, ~fully landed already)
    if (wv < 4) compute_store<4, false>(bufA, wt, on, oc0, 0, (rp0 + 0) * 2, lane, 0, 0, t, wv);
    else        compute_store<3, false>(bufA, wt, on, oc0, 4, (rp0 + 0) * 2, lane, 0, 0, t, wv);
    __builtin_amdgcn_sched_barrier(0);
    __builtin_amdgcn_s_barrier();                            // all done reading bufA
    __builtin_amdgcn_sched_barrier(0);

    // T1 from bufB, stage T2 -> bufA at tap3
    if (wv < 4) compute_store<4, true>(bufB, wt, on, oc0, 0, (rp0 + 1) * 2, lane, s2, bufA, t, wv);
    else        compute_store<3, true>(bufB, wt, on, oc0, 4, (rp0 + 1) * 2, lane, s2, bufA, t, wv);
    __builtin_amdgcn_sched_barrier(0);
    __builtin_amdgcn_s_barrier();                            // all done reading bufB
    __builtin_amdgcn_sched_barrier(0);

    // T2 from bufA, stage T3 -> bufB at tap3
    if (wv < 4) compute_store<4, true>(bufA, wt, on, oc0, 0, (rp0 + 2) * 2, lane, s3, bufB, t, wv);
    else        compute_store<3, true>(bufA, wt, on, oc0, 4, (rp0 + 2) * 2, lane, s3, bufB, t, wv);
    __builtin_amdgcn_sched_barrier(0);
    __builtin_amdgcn_s_barrier();
    __builtin_amdgcn_sched_barrier(0);

    // T3 from bufB
    if (wv < 4) compute_store<4, false>(bufB, wt, on, oc0, 0, (rp0 + 3) * 2, lane, 0, 0, t, wv);
    else        compute_store<3, false>(bufB, wt, on, oc0, 4, (rp0 + 3) * 2, lane, 0, 0, t, wv);
}

// ================= fallback (ws too small): self-contained, fp32 weights =================
#define PITCH  272
#define LDSB   (4*64*PITCH)
#define NBLK   896

template<int NPF>
__device__ __forceinline__ void fb_compute(const unsigned char* xs, const float* wf,
                                           float* on, int oc0, int pf0, int r0, int lane) {
    const int l15 = lane & 15, lq = lane >> 4;
    int spb[NPF];
    #pragma unroll
    for (int k = 0; k < NPF; ++k) {
        int p = (pf0 + k) * 16 + l15;
        int r = p / 56, w = p - r * 56;
        spb[k] = ((r + 1) * 64 + (w + 1)) * PITCH + lq * 16;
    }
    f32x4 acc[2][NPF];
    #pragma unroll
    for (int f = 0; f < 2; ++f)
        #pragma unroll
        for (int k = 0; k < NPF; ++k) acc[f][k] = (f32x4){0.f, 0.f, 0.f, 0.f};
    #pragma unroll 3
    for (int tap = 0; tap < 9; ++tap) {
        const int offb  = ((tap / 3) * 64 + (tap % 3) - 65) * PITCH;
        const int wbase = tap * 16384 + oc0 * 128 + l15 * 128 + lq * 8;
        #pragma unroll
        for (int c = 0; c < 4; ++c) {
            bf16x8 a[2];
            #pragma unroll
            for (int f = 0; f < 2; ++f) {
                const float* p = wf + wbase + f * 2048 + c * 32;
                #pragma unroll
                for (int j = 0; j < 8; ++j) a[f][j] = (__bf16)p[j];
            }
            #pragma unroll
            for (int k = 0; k < NPF; ++k) {
                bf16x8 b = *(const bf16x8*)(xs + spb[k] + offb + c * 64);
                #pragma unroll
                for (int f = 0; f < 2; ++f)
                    acc[f][k] = __builtin_amdgcn_mfma_f32_16x16x32_bf16(a[f], b, acc[f][k], 0, 0, 0);
            }
        }
    }
    #pragma unroll
    for (int f = 0; f < 2; ++f)
        #pragma unroll
        for (int k = 0; k < NPF; ++k) {
            int pos = r0 * 56 + (pf0 + k) * 16 + l15;
            int oc  = oc0 + f * 16 + lq * 4;
            #pragma unroll
            for (int rr = 0; rr < 4; ++rr)
                on[(size_t)(oc + rr) * HW + pos] = acc[f][k][rr];
        }
}

__global__ __launch_bounds__(512, 4) void fb_conv_kernel(const float* __restrict__ x,
                                                         const float* __restrict__ wf,
                                                         float* __restrict__ out) {
    __shared__ __align__(16) unsigned char xs[LDSB];
    const int tid = threadIdx.x, lane = tid & 63, wv = tid >> 6;
    const int bid = blockIdx.x;
    const int swz = (bid & 7) * (NBLK / 8) + (bid >> 3);
    const int n = swz / 28, rp = swz - n * 28, r0 = rp * 2;
    if (wv < 4) {
        const float* xn = x + (size_t)n * 128 * HW;
        const int ar = r0 - 1 + wv, wi = lane - 1;
        const bool v = (ar >= 0) & (ar < IMG_H) & (wi >= 0) & (wi < IMG_W);
        const int gc = min(max(ar, 0), IMG_H - 1) * IMG_W + min(max(wi, 0), IMG_W - 1);
        unsigned char* dst = xs + (wv * 64 + lane) * PITCH;
        #pragma unroll
        for (int cg = 0; cg < 16; ++cg) {
            bf16x8 pk;
            #pragma unroll
            for (int j = 0; j < 8; ++j) {
                float f = xn[(size_t)(cg * 8 + j) * HW + gc];
                pk[j] = (__bf16)(v ? f : 0.f);
            }
            *(bf16x8*)(dst + cg * 16) = pk;
        }
    }
    __syncthreads();
    const int oc0 = (wv & 3) * 32;
    float* on = out + (size_t)n * 128 * HW;
    if (wv < 4) fb_compute<4>(xs, wf, on, oc0, 0, r0, lane);
    else        fb_compute<3>(xs, wf, on, oc0, 4, r0, lane);
}

extern "C" void kernel_launch(void* const* d_in, const int* in_sizes, int n_in,
                              void* d_out, int out_size, void* d_ws, size_t ws_size,
                              hipStream_t stream) {
    const float* x = (const float*)d_in[0];
    const float* w = (const float*)d_in[1];
    float* out = (float*)d_out;

    if (ws_size >= XT_BYTES + WB_BYTES) {
        unsigned char* xt = (unsigned char*)d_ws;
        unsigned char* wb = xt + XT_BYTES;
        wcvt_kernel<<<(WGRAN + 255) / 256, 256, 0, stream>>>(w, wb);
        xprep_kernel<<<PBLK, 256, 0, stream>>>(x, xt);
        conv_kernel<<<CBLK, 512, 0, stream>>>(xt, wb, out);
    } else {
        fb_conv_kernel<<<NBLK, 512, 0, stream>>>(x, w, out);
    }
}